// Round 10
// baseline (344.873 us; speedup 1.0000x reference)
//
#include <hip/hip_runtime.h>
#include <float.h>

#define ALPHA 0.2f
__device__ __forceinline__ float leakyf(float x) { return x > 0.0f ? x : ALPHA * x; }

__device__ __forceinline__ unsigned short f2bf(float f) {
    unsigned u = __float_as_uint(f);
    return (unsigned short)((u + 0x7FFFu + ((u >> 16) & 1u)) >> 16);
}
__device__ __forceinline__ float bflo(unsigned u) { return __uint_as_float(u << 16); }
__device__ __forceinline__ float bfhi(unsigned u) { return __uint_as_float(u & 0xFFFF0000u); }

typedef short bf16x8 __attribute__((ext_vector_type(8)));
typedef float f32x4 __attribute__((ext_vector_type(4)));

struct Ptr4i { const int* p0; const int* p1; const int* p2; const int* p3; };
struct PrepM { const float* W; const float* b; const float* attA; const float* attB; };

// ---------- prep: fragment-linear bf16 W (+ folded attention-dot cols) + bcnt zero ----------
__global__ __launch_bounds__(256) void prep_kernel(
    PrepM m0, PrepM m1, PrepM m2, PrepM m3, PrepM m4, PrepM m5,
    bf16x8* __restrict__ wfrag, float* __restrict__ cd,
    int* __restrict__ bcnt, int nz)
{
    int mi = blockIdx.x;
    PrepM mm = (mi == 0) ? m0 : (mi == 1) ? m1 : (mi == 2) ? m2 :
               (mi == 3) ? m3 : (mi == 4) ? m4 : m5;
    int part = blockIdx.y;
    if (mi == 0 && part == 0) {
        for (int i = threadIdx.x; i < nz; i += 256) bcnt[i] = 0;
    }
    for (int ii = 0; ii < 3; ++ii) {
        int c = part * 576 + threadIdx.x + 256 * ii;
        if (c >= part * 576 + 576) continue;
        int t = c >> 8;
        int kstep = (c >> 6) & 3;
        int l = c & 63;
        int k0 = kstep * 32 + (l >> 4) * 8;
        bf16x8 out;
        if (t < 8) {
            int col = t * 16 + (l & 15);
            #pragma unroll
            for (int j = 0; j < 8; ++j)
                out[j] = (short)f2bf(mm.W[(size_t)(k0 + j) * 128 + col]);
        } else {
            int cl = l & 15;
            const float* att = nullptr; int h = 0;
            if (cl < 4 && mm.attA) { att = mm.attA; h = cl; }
            else if (cl >= 4 && cl < 8 && mm.attB) { att = mm.attB; h = cl - 4; }
            #pragma unroll
            for (int j = 0; j < 8; ++j) {
                float s = 0.f;
                if (att) {
                    const float* wrow = mm.W + (size_t)(k0 + j) * 128 + h * 32;
                    for (int d = 0; d < 32; ++d) s += wrow[d] * att[h * 32 + d];
                }
                out[j] = (short)f2bf(s);
            }
        }
        wfrag[(size_t)mi * 2304 + c] = out;
    }
    if (part == 0 && threadIdx.x < 8) {
        int cl = threadIdx.x;
        float s = 0.f;
        const float* att = nullptr; int h = 0;
        if (cl < 4 && mm.attA) { att = mm.attA; h = cl; }
        else if (cl >= 4 && mm.attB) { att = mm.attB; h = cl - 4; }
        if (att) for (int d = 0; d < 32; ++d) s += mm.b[h * 32 + d] * att[h * 32 + d];
        cd[mi * 8 + cl] = s;
    }
}

// ---------- MFMA compute + epilogue (all outputs bf16) ----------
__device__ __forceinline__ void mfma_compute_store(
    const short* xs_s, const short* wl_s, int row0, int N,
    const float* __restrict__ b, unsigned short* __restrict__ o16,
    float* __restrict__ dotA, float* __restrict__ dotB, const float* __restrict__ cd)
{
    int l = threadIdx.x & 63, w = threadIdx.x >> 6;
    int cl = l & 15, gq = l >> 4;
    f32x4 acc[9];
    #pragma unroll
    for (int t = 0; t < 9; ++t) acc[t] = (f32x4){0.f, 0.f, 0.f, 0.f};
    int arow = w * 16 + cl;
    #pragma unroll
    for (int ks = 0; ks < 4; ++ks) {
        int k8 = ks * 4 + gq;
        bf16x8 a = *(const bf16x8*)((const char*)xs_s + arow * 256 + ((k8 * 16) ^ ((arow & 7) << 4)));
        #pragma unroll
        for (int t = 0; t < 9; ++t) {
            bf16x8 bf = *(const bf16x8*)((const char*)wl_s + ((t * 4 + ks) * 64 + l) * 16);
            acc[t] = __builtin_amdgcn_mfma_f32_16x16x32_bf16(a, bf, acc[t], 0, 0, 0);
        }
    }
    int rbase = row0 + w * 16 + gq * 4;
    #pragma unroll
    for (int t = 0; t < 8; ++t) {
        int col = t * 16 + cl;
        float bias = b[col];
        #pragma unroll
        for (int j = 0; j < 4; ++j) {
            int row = rbase + j;
            if (row < N) o16[(size_t)row * 128 + col] = f2bf(acc[t][j] + bias);
        }
    }
    if (cl < 8) {
        float cdv = cd[cl];
        float* dp = (cl < 4) ? dotA : dotB;
        int h = cl & 3;
        if (dp) {
            #pragma unroll
            for (int j = 0; j < 4; ++j) {
                int row = rbase + j;
                if (row < N) dp[(size_t)row * 4 + h] = acc[8][j] + cdv;
            }
        }
    }
}

struct Lin3Cfg {
    const float* x; int N; int blocks;
    const bf16x8* wfrag; const float* cd;
    const float* b0; unsigned short* o0; float* dA0; float* dB0;
    const float* b1; unsigned short* o1; float* dA1;
    const float* b2; unsigned short* o2; float* dA2;
};

// ---------- merged fused 3-matrix MFMA linear (P and A in one dispatch) ----------
__global__ __launch_bounds__(256) void lin3_mfma_kernel(Lin3Cfg cP, Lin3Cfg cA)
{
    __shared__ short xs_s[64 * 128];
    __shared__ short wl_s[2304 * 8];
    const bool isP = blockIdx.x < (unsigned)cP.blocks;
    const Lin3Cfg& c = isP ? cP : cA;
    const int bx = isP ? blockIdx.x : (blockIdx.x - cP.blocks);
    const int row0 = bx * 64;
    const int N = c.N;

    #pragma unroll
    for (int ii = 0; ii < 4; ++ii) {
        int ci = threadIdx.x + 256 * ii;
        int r = ci >> 4, k8 = ci & 15;
        int srcrow = row0 + r; if (srcrow >= N) srcrow = N - 1;
        const float4* gp = (const float4*)(c.x + (size_t)srcrow * 128 + k8 * 8);
        float4 v0 = gp[0], v1 = gp[1];
        bf16x8 p;
        p[0] = (short)f2bf(v0.x); p[1] = (short)f2bf(v0.y);
        p[2] = (short)f2bf(v0.z); p[3] = (short)f2bf(v0.w);
        p[4] = (short)f2bf(v1.x); p[5] = (short)f2bf(v1.y);
        p[6] = (short)f2bf(v1.z); p[7] = (short)f2bf(v1.w);
        *(bf16x8*)((char*)xs_s + r * 256 + ((k8 * 16) ^ ((r & 7) << 4))) = p;
    }
    #pragma unroll
    for (int ii = 0; ii < 9; ++ii)
        ((bf16x8*)wl_s)[threadIdx.x + 256 * ii] = c.wfrag[threadIdx.x + 256 * ii];
    __syncthreads();
    mfma_compute_store(xs_s, wl_s, row0, N, c.b0, c.o0, c.dA0, c.dB0, c.cd);

    __syncthreads();
    #pragma unroll
    for (int ii = 0; ii < 9; ++ii)
        ((bf16x8*)wl_s)[threadIdx.x + 256 * ii] = c.wfrag[2304 + threadIdx.x + 256 * ii];
    __syncthreads();
    mfma_compute_store(xs_s, wl_s, row0, N, c.b1, c.o1, c.dA1, nullptr, c.cd + 8);

    __syncthreads();
    #pragma unroll
    for (int ii = 0; ii < 9; ++ii)
        ((bf16x8*)wl_s)[threadIdx.x + 256 * ii] = c.wfrag[2 * 2304 + threadIdx.x + 256 * ii];
    __syncthreads();
    mfma_compute_store(xs_s, wl_s, row0, N, c.b2, c.o2, c.dA2, nullptr, c.cd + 16);
}

// ================= bucketed CSR build (buckets of 1024 dsts) =================

// ---- pass A1: per-bucket edge counts (per-wave LDS histograms) ----
__global__ __launch_bounds__(256) void binA_count_kernel(Ptr4i dsts, int* __restrict__ bcnt,
                                                         int nbkMax, int E)
{
    __shared__ int lh[4][128];
    ((int*)lh)[threadIdx.x] = 0;
    ((int*)lh)[threadIdx.x + 256] = 0;
    __syncthreads();
    int r = blockIdx.y;
    int w = threadIdx.x >> 6;
    const int* dst = (r == 0) ? dsts.p0 : (r == 1) ? dsts.p1 : (r == 2) ? dsts.p2 : dsts.p3;
    int base = blockIdx.x * 4096;
    #pragma unroll 4
    for (int ii = 0; ii < 16; ++ii) {
        int i = base + threadIdx.x + 256 * ii;
        if (i < E) atomicAdd(&lh[w][dst[i] >> 10], 1);
    }
    __syncthreads();
    if (threadIdx.x < 128) {
        int v = lh[0][threadIdx.x] + lh[1][threadIdx.x] + lh[2][threadIdx.x] + lh[3][threadIdx.x];
        if (v && threadIdx.x < nbkMax) atomicAdd(&bcnt[r * nbkMax + threadIdx.x], v);
    }
}

// ---- parallel scan of bucket counts ----
__global__ __launch_bounds__(512) void bin_scan_kernel(const int* __restrict__ bcnt,
                                                       int* __restrict__ bbase,
                                                       int* __restrict__ gwptr, int nbkMax)
{
    __shared__ int sh[4][128];
    int r = threadIdx.x >> 7, b = threadIdx.x & 127;
    int v = (b < nbkMax) ? bcnt[r * nbkMax + b] : 0;
    sh[r][b] = v;
    __syncthreads();
    #pragma unroll
    for (int off = 1; off < 128; off <<= 1) {
        int y = (b >= off) ? sh[r][b - off] : 0;
        __syncthreads();
        sh[r][b] += y;
        __syncthreads();
    }
    if (b < nbkMax) {
        int ex = sh[r][b] - v;
        bbase[r * nbkMax + b] = ex;
        gwptr[r * nbkMax + b] = ex;
    }
}

// ---- pass A2: LDS-binned scatter into bucket-ordered packed array ----
__global__ __launch_bounds__(256) void binA_scatter_kernel(Ptr4i dsts, Ptr4i srcs,
    int* __restrict__ gwptr, unsigned* __restrict__ packed, int nbkMax, int E)
{
    __shared__ int lh[128], loff[128], lptr[128], gb[128];
    __shared__ unsigned stg[4096];
    __shared__ unsigned short sb[4096];
    if (threadIdx.x < 128) lh[threadIdx.x] = 0;
    __syncthreads();
    int r = blockIdx.y;
    const int* dst = (r == 0) ? dsts.p0 : (r == 1) ? dsts.p1 : (r == 2) ? dsts.p2 : dsts.p3;
    const int* src = (r == 0) ? srcs.p0 : (r == 1) ? srcs.p1 : (r == 2) ? srcs.p2 : srcs.p3;
    int base = blockIdx.x * 4096;
    int d16[16], s16[16];
    #pragma unroll 4
    for (int ii = 0; ii < 16; ++ii) {
        int i = base + threadIdx.x + 256 * ii;
        if (i < E) {
            d16[ii] = dst[i];
            s16[ii] = src[i];
            atomicAdd(&lh[d16[ii] >> 10], 1);
        } else d16[ii] = -1;
    }
    __syncthreads();
    if (threadIdx.x == 0) {
        int run = 0;
        for (int b = 0; b < nbkMax; ++b) { loff[b] = run; lptr[b] = run; run += lh[b]; }
    }
    __syncthreads();
    #pragma unroll 4
    for (int ii = 0; ii < 16; ++ii) {
        if (d16[ii] >= 0) {
            int b = d16[ii] >> 10;
            int p = atomicAdd(&lptr[b], 1);
            stg[p] = ((unsigned)s16[ii] << 10) | (unsigned)(d16[ii] & 1023);
            sb[p] = (unsigned short)b;
        }
    }
    __syncthreads();
    if (threadIdx.x < nbkMax && lh[threadIdx.x])
        gb[threadIdx.x] = atomicAdd(&gwptr[r * nbkMax + threadIdx.x], lh[threadIdx.x]);
    __syncthreads();
    int tot = min(4096, E - base);
    #pragma unroll 4
    for (int ii = 0; ii < 16; ++ii) {
        int p = threadIdx.x + 256 * ii;
        if (p < tot) {
            int b = sb[p];
            packed[(size_t)r * E + gb[b] + (p - loff[b])] = stg[p];
        }
    }
}

// ---- pass B: per-bucket CSR finalize ----
__global__ __launch_bounds__(256) void binB_build_kernel(
    const unsigned* __restrict__ packed, const int* __restrict__ bcnt, const int* __restrict__ bbase,
    int nbkMax, int4 Ns, int E, int stride,
    int* __restrict__ start, int* __restrict__ deg, int* __restrict__ csrc)
{
    int r = blockIdx.y, b = blockIdx.x;
    int N = (r == 0) ? Ns.x : (r == 1) ? Ns.y : (r == 2) ? Ns.z : Ns.w;
    int dst0 = b << 10;
    if (dst0 >= N) return;
    int cnt  = bcnt[r * nbkMax + b];
    int base = bbase[r * nbkMax + b];
    __shared__ int hist[1024];
    __shared__ int sums[256];
    #pragma unroll
    for (int i = 0; i < 4; ++i) hist[threadIdx.x * 4 + i] = 0;
    __syncthreads();
    const unsigned* pk = packed + (size_t)r * E + base;
    for (int i = threadIdx.x; i < cnt; i += 256)
        atomicAdd(&hist[pk[i] & 1023], 1);
    __syncthreads();
    int v4[4], s = 0;
    #pragma unroll
    for (int i = 0; i < 4; ++i) { v4[i] = hist[threadIdx.x * 4 + i]; s += v4[i]; }
    sums[threadIdx.x] = s;
    __syncthreads();
    #pragma unroll
    for (int off = 1; off < 256; off <<= 1) {
        int y = (threadIdx.x >= off) ? sums[threadIdx.x - off] : 0;
        __syncthreads();
        sums[threadIdx.x] += y;
        __syncthreads();
    }
    int run = sums[threadIdx.x] - s;
    int* st = start + (size_t)r * stride;
    int* dg = deg   + (size_t)r * stride;
    #pragma unroll
    for (int i = 0; i < 4; ++i) {
        int idx = threadIdx.x * 4 + i;
        int d = dst0 + idx;
        if (d < N) { dg[d] = v4[i]; st[d] = base + run; }
        hist[idx] = run;
        run += v4[i];
    }
    __syncthreads();
    int* cs = csrc + (size_t)r * E + base;
    for (int i = threadIdx.x; i < cnt; i += 256) {
        unsigned e = pk[i];
        int p = atomicAdd(&hist[e & 1023], 1);
        cs[p] = (int)(e >> 10);
    }
}

// ---------- merged per-dst fused GAT: 16 lanes/edge x 4 slots, 2-deep unroll, bf16 self ----------
struct GatRel {
    const int* start; const int* deg; const int* csrc;
    const unsigned short* Wh; const float* es; const float* ed;
};
struct GatCfg { float* out; const unsigned short* self; int Nd; int blocks; GatRel rel0, rel1; };

__global__ __launch_bounds__(256) void gat_node_kernel(GatCfg cP, GatCfg cA)
{
    const bool isP = blockIdx.x < (unsigned)cP.blocks;
    const GatCfg& c = isP ? cP : cA;
    const int bx = isP ? blockIdx.x : (blockIdx.x - cP.blocks);
    int gid = bx * 256 + threadIdx.x;
    int d = gid >> 6;
    if (d >= c.Nd) return;
    int lane = threadIdx.x & 63;
    int q = lane >> 4;        // edge slot
    int l = lane & 15;        // dim group: dims 8l..8l+7
    int h = l >> 2;           // head

    float a0 = 0.f, a1 = 0.f, a2 = 0.f, a3 = 0.f;
    float a4 = 0.f, a5 = 0.f, a6 = 0.f, a7 = 0.f;

    #pragma unroll
    for (int rel = 0; rel < 2; ++rel) {
        const GatRel& R = rel ? c.rel1 : c.rel0;
        int st = R.start[d];
        int n  = R.deg[d];
        if (n == 0) continue;
        const uint4* W4 = (const uint4*)R.Wh;   // row = 128 bf16 = 16 uint4
        float edv = R.ed[(size_t)d * 4 + h];
        float sum = 0.f;
        float m0 = 0.f, m1 = 0.f, m2 = 0.f, m3 = 0.f;
        float m4 = 0.f, m5 = 0.f, m6 = 0.f, m7 = 0.f;
        int j = q;
        for (; j + 4 < n; j += 8) {
            int s0 = R.csrc[st + j];
            int s1 = R.csrc[st + j + 4];
            float p0 = __expf(leakyf(R.es[(size_t)s0 * 4 + h] + edv));
            float p1 = __expf(leakyf(R.es[(size_t)s1 * 4 + h] + edv));
            uint4 w0 = W4[(size_t)s0 * 16 + l];
            uint4 w1 = W4[(size_t)s1 * 16 + l];
            sum += p0 + p1;
            m0 += p0 * bflo(w0.x) + p1 * bflo(w1.x);
            m1 += p0 * bfhi(w0.x) + p1 * bfhi(w1.x);
            m2 += p0 * bflo(w0.y) + p1 * bflo(w1.y);
            m3 += p0 * bfhi(w0.y) + p1 * bfhi(w1.y);
            m4 += p0 * bflo(w0.z) + p1 * bflo(w1.z);
            m5 += p0 * bfhi(w0.z) + p1 * bfhi(w1.z);
            m6 += p0 * bflo(w0.w) + p1 * bflo(w1.w);
            m7 += p0 * bfhi(w0.w) + p1 * bfhi(w1.w);
        }
        if (j < n) {
            int s0 = R.csrc[st + j];
            float p0 = __expf(leakyf(R.es[(size_t)s0 * 4 + h] + edv));
            uint4 w0 = W4[(size_t)s0 * 16 + l];
            sum += p0;
            m0 += p0 * bflo(w0.x); m1 += p0 * bfhi(w0.x);
            m2 += p0 * bflo(w0.y); m3 += p0 * bfhi(w0.y);
            m4 += p0 * bflo(w0.z); m5 += p0 * bfhi(w0.z);
            m6 += p0 * bflo(w0.w); m7 += p0 * bfhi(w0.w);
        }
        #pragma unroll
        for (int off = 16; off < 64; off <<= 1) {
            sum += __shfl_xor(sum, off, 64);
            m0 += __shfl_xor(m0, off, 64); m1 += __shfl_xor(m1, off, 64);
            m2 += __shfl_xor(m2, off, 64); m3 += __shfl_xor(m3, off, 64);
            m4 += __shfl_xor(m4, off, 64); m5 += __shfl_xor(m5, off, 64);
            m6 += __shfl_xor(m6, off, 64); m7 += __shfl_xor(m7, off, 64);
        }
        float inv = 1.0f / sum;
        a0 += m0 * inv; a1 += m1 * inv; a2 += m2 * inv; a3 += m3 * inv;
        a4 += m4 * inv; a5 += m5 * inv; a6 += m6 * inv; a7 += m7 * inv;
    }
    if (lane < 16) {
        // bf16 self term (8 dims = one uint4)
        uint4 sv = ((const uint4*)(c.self + (size_t)d * 128))[l];
        float4 o0, o1;
        o0.x = fmaxf(a0 + bflo(sv.x), 0.f); o0.y = fmaxf(a1 + bfhi(sv.x), 0.f);
        o0.z = fmaxf(a2 + bflo(sv.y), 0.f); o0.w = fmaxf(a3 + bfhi(sv.y), 0.f);
        o1.x = fmaxf(a4 + bflo(sv.z), 0.f); o1.y = fmaxf(a5 + bfhi(sv.z), 0.f);
        o1.z = fmaxf(a6 + bflo(sv.w), 0.f); o1.w = fmaxf(a7 + bfhi(sv.w), 0.f);
        float4* ow = (float4*)(c.out + (size_t)d * 128);
        ow[l * 2] = o0; ow[l * 2 + 1] = o1;
    }
}

extern "C" void kernel_launch(void* const* d_in, const int* in_sizes, int n_in,
                              void* d_out, int out_size, void* d_ws, size_t ws_size,
                              hipStream_t stream)
{
    const float* feat_P = (const float*)d_in[0];
    const float* feat_A = (const float*)d_in[1];
    const int* src_p2p = (const int*)d_in[2];
    const int* dst_p2p = (const int*)d_in[3];
    const int* src_p2a = (const int*)d_in[4];
    const int* dst_p2a = (const int*)d_in[5];
    const int* src_a2p = (const int*)d_in[6];
    const int* dst_a2p = (const int*)d_in[7];
    const int* src_a2a = (const int*)d_in[8];
    const int* dst_a2a = (const int*)d_in[9];
    const float* W_P   = (const float*)d_in[10]; const float* b_P   = (const float*)d_in[11];
    const float* W_A   = (const float*)d_in[12]; const float* b_A   = (const float*)d_in[13];
    const float* W_p2p = (const float*)d_in[14]; const float* b_p2p = (const float*)d_in[15];
    const float* W_p2a = (const float*)d_in[16]; const float* b_p2a = (const float*)d_in[17];
    const float* W_a2p = (const float*)d_in[18]; const float* b_a2p = (const float*)d_in[19];
    const float* W_a2a = (const float*)d_in[20]; const float* b_a2a = (const float*)d_in[21];
    const float* att_p2p_src = (const float*)d_in[22];
    const float* att_p2p_dst = (const float*)d_in[23];
    const float* att_p2a_src = (const float*)d_in[24];
    const float* att_p2a_dst = (const float*)d_in[25];
    const float* att_a2p_src = (const float*)d_in[26];
    const float* att_a2p_dst = (const float*)d_in[27];
    const float* att_a2a_src = (const float*)d_in[28];
    const float* att_a2a_dst = (const float*)d_in[29];

    const int NP = in_sizes[0] / 128;
    const int NA = in_sizes[1] / 128;
    const int E  = in_sizes[2];
    const int stride = (NP > NA) ? NP : NA;
    const int nbkMax = (stride + 1023) >> 10;   // <= 128

    float* outP = (float*)d_out;
    float* outA = (float*)d_out + (size_t)NP * 128;

    char* ws = (char*)d_ws;
    size_t off = 0;
    auto alloc = [&](size_t bytes) -> void* {
        void* p = ws + off;
        off += (bytes + 255) & ~(size_t)255;
        return p;
    };
    unsigned short* Whp2p = (unsigned short*)alloc((size_t)NP * 128 * 2);
    unsigned short* Whp2a = (unsigned short*)alloc((size_t)NP * 128 * 2);
    unsigned short* Wha2p = (unsigned short*)alloc((size_t)NA * 128 * 2);
    unsigned short* Wha2a = (unsigned short*)alloc((size_t)NA * 128 * 2);
    unsigned short* selfP = (unsigned short*)alloc((size_t)NP * 128 * 2);
    unsigned short* selfA = (unsigned short*)alloc((size_t)NA * 128 * 2);
    float* es_p2p = (float*)alloc((size_t)NP * 16);
    float* es_p2a = (float*)alloc((size_t)NP * 16);
    float* es_a2p = (float*)alloc((size_t)NA * 16);
    float* es_a2a = (float*)alloc((size_t)NA * 16);
    float* ed_p2p = (float*)alloc((size_t)NP * 16);
    float* ed_a2p = (float*)alloc((size_t)NP * 16);
    float* ed_p2a = (float*)alloc((size_t)NA * 16);
    float* ed_a2a = (float*)alloc((size_t)NA * 16);
    int* deg    = (int*)alloc((size_t)4 * stride * 4);
    int* start  = (int*)alloc((size_t)4 * stride * 4);
    int* csrc   = (int*)alloc((size_t)4 * E * 4);
    unsigned* packed = (unsigned*)alloc((size_t)4 * E * 4);
    int* bcnt   = (int*)alloc((size_t)4 * nbkMax * 4);
    int* bbase  = (int*)alloc((size_t)4 * nbkMax * 4);
    int* gwptr  = (int*)alloc((size_t)4 * nbkMax * 4);
    bf16x8* wfrag = (bf16x8*)alloc((size_t)6 * 2304 * 16);
    float* cd     = (float*)alloc((size_t)6 * 8 * 4);

    // relation order: 0=p2p(dst P), 1=a2p(dst P), 2=p2a(dst A), 3=a2a(dst A)
    Ptr4i dsts = {dst_p2p, dst_a2p, dst_p2a, dst_a2a};
    Ptr4i srcs = {src_p2p, src_a2p, src_p2a, src_a2a};
    int4 Ns = make_int4(NP, NP, NA, NA);

    // ---- 0) prep weights (+ zero bcnt) ----
    {
        PrepM m0 = {W_P,   b_P,   att_p2p_dst, att_a2p_dst};
        PrepM m1 = {W_p2p, b_p2p, att_p2p_src, nullptr};
        PrepM m2 = {W_p2a, b_p2a, att_p2a_src, nullptr};
        PrepM m3 = {W_A,   b_A,   att_p2a_dst, att_a2a_dst};
        PrepM m4 = {W_a2p, b_a2p, att_a2p_src, nullptr};
        PrepM m5 = {W_a2a, b_a2a, att_a2a_src, nullptr};
        prep_kernel<<<dim3(6, 4), 256, 0, stream>>>(m0, m1, m2, m3, m4, m5, wfrag, cd,
                                                    bcnt, 4 * nbkMax);
    }

    // ---- 1) merged MFMA linears (self bf16 side buffer) ----
    {
        Lin3Cfg cP = {feat_P, NP, (NP + 63) / 64, wfrag, cd,
                      b_P, selfP, ed_p2p, ed_a2p,
                      b_p2p, Whp2p, es_p2p,
                      b_p2a, Whp2a, es_p2a};
        Lin3Cfg cA = {feat_A, NA, (NA + 63) / 64, wfrag + (size_t)3 * 2304, cd + 24,
                      b_A, selfA, ed_p2a, ed_a2a,
                      b_a2p, Wha2p, es_a2p,
                      b_a2a, Wha2a, es_a2a};
        lin3_mfma_kernel<<<cP.blocks + cA.blocks, 256, 0, stream>>>(cP, cA);
    }

    // ---- 2) bucketed CSR build ----
    {
        dim3 gA((E + 4095) / 4096, 4);
        binA_count_kernel<<<gA, 256, 0, stream>>>(dsts, bcnt, nbkMax, E);
        bin_scan_kernel<<<1, 512, 0, stream>>>(bcnt, bbase, gwptr, nbkMax);
        binA_scatter_kernel<<<gA, 256, 0, stream>>>(dsts, srcs, gwptr, packed, nbkMax, E);
        binB_build_kernel<<<dim3(nbkMax, 4), 256, 0, stream>>>(packed, bcnt, bbase,
            nbkMax, Ns, E, stride, start, deg, csrc);
    }

    // ---- 3) merged per-dst aggregation (+self +relu) ----
    {
        GatCfg cP = {outP, selfP, NP, (NP * 64 + 255) / 256,
            {start + 0 * (size_t)stride, deg + 0 * (size_t)stride, csrc + 0 * (size_t)E, Whp2p, es_p2p, ed_p2p},
            {start + 1 * (size_t)stride, deg + 1 * (size_t)stride, csrc + 1 * (size_t)E, Wha2p, es_a2p, ed_a2p}};
        GatCfg cA = {outA, selfA, NA, (NA * 64 + 255) / 256,
            {start + 2 * (size_t)stride, deg + 2 * (size_t)stride, csrc + 2 * (size_t)E, Whp2a, es_p2a, ed_p2a},
            {start + 3 * (size_t)stride, deg + 3 * (size_t)stride, csrc + 3 * (size_t)E, Wha2a, es_a2a, ed_a2a}};
        gat_node_kernel<<<cP.blocks + cA.blocks, 256, 0, stream>>>(cP, cA);
    }
}

// Round 11
// 331.982 us; speedup vs baseline: 1.0388x; 1.0388x over previous
//
#include <hip/hip_runtime.h>
#include <float.h>

#define ALPHA 0.2f
__device__ __forceinline__ float leakyf(float x) { return x > 0.0f ? x : ALPHA * x; }

__device__ __forceinline__ unsigned short f2bf(float f) {
    unsigned u = __float_as_uint(f);
    return (unsigned short)((u + 0x7FFFu + ((u >> 16) & 1u)) >> 16);
}
__device__ __forceinline__ float bflo(unsigned u) { return __uint_as_float(u << 16); }
__device__ __forceinline__ float bfhi(unsigned u) { return __uint_as_float(u & 0xFFFF0000u); }

typedef short bf16x8 __attribute__((ext_vector_type(8)));
typedef float f32x4 __attribute__((ext_vector_type(4)));

struct Ptr4i { const int* p0; const int* p1; const int* p2; const int* p3; };
struct PrepM { const float* W; const float* b; const float* attA; const float* attB; };

// ========== K1: merged  per-bucket count (partials, no atomics)  ∪  weight prep ==========
__global__ __launch_bounds__(256) void prep_count_kernel(
    PrepM m0, PrepM m1, PrepM m2, PrepM m3, PrepM m4, PrepM m5,
    bf16x8* __restrict__ wfrag, float* __restrict__ cd,
    Ptr4i dsts, int* __restrict__ pcnt, int nblkE, int E, int nCount)
{
    __shared__ int lh[4][128];
    if ((int)blockIdx.x < nCount) {
        // ---- count path: per-block partial bucket histogram ----
        ((int*)lh)[threadIdx.x] = 0;
        ((int*)lh)[threadIdx.x + 256] = 0;
        __syncthreads();
        int cb = blockIdx.x;
        int r = cb & 3, bx = cb >> 2;
        int w = threadIdx.x >> 6;
        const int* dst = (r == 0) ? dsts.p0 : (r == 1) ? dsts.p1 : (r == 2) ? dsts.p2 : dsts.p3;
        int base = bx * 4096;
        #pragma unroll 4
        for (int ii = 0; ii < 16; ++ii) {
            int i = base + threadIdx.x + 256 * ii;
            if (i < E) atomicAdd(&lh[w][dst[i] >> 10], 1);
        }
        __syncthreads();
        if (threadIdx.x < 128)
            pcnt[((size_t)r * nblkE + bx) * 128 + threadIdx.x] =
                lh[0][threadIdx.x] + lh[1][threadIdx.x] + lh[2][threadIdx.x] + lh[3][threadIdx.x];
        return;
    }
    // ---- prep path ----
    int pb = blockIdx.x - nCount;
    int mi = pb >> 2;
    int part = pb & 3;
    PrepM mm = (mi == 0) ? m0 : (mi == 1) ? m1 : (mi == 2) ? m2 :
               (mi == 3) ? m3 : (mi == 4) ? m4 : m5;
    for (int ii = 0; ii < 3; ++ii) {
        int c = part * 576 + threadIdx.x + 256 * ii;
        if (c >= part * 576 + 576) continue;
        int t = c >> 8;
        int kstep = (c >> 6) & 3;
        int l = c & 63;
        int k0 = kstep * 32 + (l >> 4) * 8;
        bf16x8 out;
        if (t < 8) {
            int col = t * 16 + (l & 15);
            #pragma unroll
            for (int j = 0; j < 8; ++j)
                out[j] = (short)f2bf(mm.W[(size_t)(k0 + j) * 128 + col]);
        } else {
            int cl = l & 15;
            const float* att = nullptr; int h = 0;
            if (cl < 4 && mm.attA) { att = mm.attA; h = cl; }
            else if (cl >= 4 && cl < 8 && mm.attB) { att = mm.attB; h = cl - 4; }
            #pragma unroll
            for (int j = 0; j < 8; ++j) {
                float s = 0.f;
                if (att) {
                    const float* wrow = mm.W + (size_t)(k0 + j) * 128 + h * 32;
                    for (int d = 0; d < 32; ++d) s += wrow[d] * att[h * 32 + d];
                }
                out[j] = (short)f2bf(s);
            }
        }
        wfrag[(size_t)mi * 2304 + c] = out;
    }
    if (part == 0 && threadIdx.x < 8) {
        int cl = threadIdx.x;
        float s = 0.f;
        const float* att = nullptr; int h = 0;
        if (cl < 4 && mm.attA) { att = mm.attA; h = cl; }
        else if (cl >= 4 && mm.attB) { att = mm.attB; h = cl - 4; }
        if (att) for (int d = 0; d < 32; ++d) s += mm.b[h * 32 + d] * att[h * 32 + d];
        cd[mi * 8 + cl] = s;
    }
}

// ========== K2: reduce partials + exclusive scan ==========
__global__ __launch_bounds__(512) void scan_kernel(
    const int* __restrict__ pcnt, int nblkE,
    int* __restrict__ bcnt, int* __restrict__ bbase, int* __restrict__ gwptr, int nbkMax)
{
    __shared__ int sh[4][128];
    int r = threadIdx.x >> 7, b = threadIdx.x & 127;
    int v = 0;
    if (b < nbkMax)
        for (int i = 0; i < nblkE; ++i)
            v += pcnt[((size_t)r * nblkE + i) * 128 + b];
    sh[r][b] = v;
    __syncthreads();
    #pragma unroll
    for (int off = 1; off < 128; off <<= 1) {
        int y = (b >= off) ? sh[r][b - off] : 0;
        __syncthreads();
        sh[r][b] += y;
        __syncthreads();
    }
    if (b < nbkMax) {
        int ex = sh[r][b] - v;
        bcnt[r * nbkMax + b]  = v;
        bbase[r * nbkMax + b] = ex;
        gwptr[r * nbkMax + b] = ex;
    }
}

// ---------- MFMA compute + epilogue for one matrix ----------
__device__ __forceinline__ void mfma_compute_store(
    const short* xs_s, const short* wl_s, int row0, int N,
    const float* __restrict__ b, float* __restrict__ o32, unsigned short* __restrict__ o16,
    float* __restrict__ dotA, float* __restrict__ dotB, const float* __restrict__ cd)
{
    int l = threadIdx.x & 63, w = threadIdx.x >> 6;
    int cl = l & 15, gq = l >> 4;
    f32x4 acc[9];
    #pragma unroll
    for (int t = 0; t < 9; ++t) acc[t] = (f32x4){0.f, 0.f, 0.f, 0.f};
    int arow = w * 16 + cl;
    #pragma unroll
    for (int ks = 0; ks < 4; ++ks) {
        int k8 = ks * 4 + gq;
        bf16x8 a = *(const bf16x8*)((const char*)xs_s + arow * 256 + ((k8 * 16) ^ ((arow & 7) << 4)));
        #pragma unroll
        for (int t = 0; t < 9; ++t) {
            bf16x8 bf = *(const bf16x8*)((const char*)wl_s + ((t * 4 + ks) * 64 + l) * 16);
            acc[t] = __builtin_amdgcn_mfma_f32_16x16x32_bf16(a, bf, acc[t], 0, 0, 0);
        }
    }
    int rbase = row0 + w * 16 + gq * 4;
    #pragma unroll
    for (int t = 0; t < 8; ++t) {
        int col = t * 16 + cl;
        float bias = b[col];
        #pragma unroll
        for (int j = 0; j < 4; ++j) {
            int row = rbase + j;
            if (row < N) {
                float v = acc[t][j] + bias;
                if (o32) o32[(size_t)row * 128 + col] = v;
                else     o16[(size_t)row * 128 + col] = f2bf(v);
            }
        }
    }
    if (cl < 8) {
        float cdv = cd[cl];
        float* dp = (cl < 4) ? dotA : dotB;
        int h = cl & 3;
        if (dp) {
            #pragma unroll
            for (int j = 0; j < 4; ++j) {
                int row = rbase + j;
                if (row < N) dp[(size_t)row * 4 + h] = acc[8][j] + cdv;
            }
        }
    }
}

struct Lin3Cfg {
    const float* x; int N; int blocks;
    const bf16x8* wfrag; const float* cd;
    const float* b0; float* o0; float* dA0; float* dB0;
    const float* b1; unsigned short* o1; float* dA1;
    const float* b2; unsigned short* o2; float* dA2;
};

// ========== K3: merged  LDS-binned scatter  ∪  fused 3-matrix MFMA linear (P+A) ==========
__global__ __launch_bounds__(256) void lin3_scatter_kernel(
    Lin3Cfg cP, Lin3Cfg cA, Ptr4i dsts, Ptr4i srcs,
    int* __restrict__ gwptr, unsigned* __restrict__ packed, int nbkMax, int E, int nScat)
{
    __shared__ __align__(16) char smem[53248];
    if ((int)blockIdx.x < nScat) {
        // ---- scatter path (26.6 KB of smem) ----
        int* lh   = (int*)smem;
        int* loff = lh + 128;
        int* lptr = lh + 256;
        int* gb   = lh + 384;
        unsigned* stg = (unsigned*)(smem + 2048);
        unsigned short* sb = (unsigned short*)(smem + 2048 + 16384);
        if (threadIdx.x < 128) lh[threadIdx.x] = 0;
        __syncthreads();
        int cb = blockIdx.x;
        int r = cb & 3, bx = cb >> 2;
        const int* dst = (r == 0) ? dsts.p0 : (r == 1) ? dsts.p1 : (r == 2) ? dsts.p2 : dsts.p3;
        const int* src = (r == 0) ? srcs.p0 : (r == 1) ? srcs.p1 : (r == 2) ? srcs.p2 : srcs.p3;
        int base = bx * 4096;
        int d16[16], s16[16];
        #pragma unroll 4
        for (int ii = 0; ii < 16; ++ii) {
            int i = base + threadIdx.x + 256 * ii;
            if (i < E) {
                d16[ii] = dst[i];
                s16[ii] = src[i];
                atomicAdd(&lh[d16[ii] >> 10], 1);
            } else d16[ii] = -1;
        }
        __syncthreads();
        if (threadIdx.x == 0) {
            int run = 0;
            for (int b = 0; b < nbkMax; ++b) { loff[b] = run; lptr[b] = run; run += lh[b]; }
        }
        __syncthreads();
        #pragma unroll 4
        for (int ii = 0; ii < 16; ++ii) {
            if (d16[ii] >= 0) {
                int b = d16[ii] >> 10;
                int p = atomicAdd(&lptr[b], 1);
                stg[p] = ((unsigned)s16[ii] << 10) | (unsigned)(d16[ii] & 1023);
                sb[p] = (unsigned short)b;
            }
        }
        __syncthreads();
        if (threadIdx.x < nbkMax && lh[threadIdx.x])
            gb[threadIdx.x] = atomicAdd(&gwptr[r * nbkMax + threadIdx.x], lh[threadIdx.x]);
        __syncthreads();
        int tot = min(4096, E - base);
        #pragma unroll 4
        for (int ii = 0; ii < 16; ++ii) {
            int p = threadIdx.x + 256 * ii;
            if (p < tot) {
                int b = sb[p];
                packed[(size_t)r * E + gb[b] + (p - loff[b])] = stg[p];
            }
        }
        return;
    }
    // ---- lin3 path (53.25 KB of smem) ----
    short* xs_s = (short*)smem;            // 16 KB
    short* wl_s = (short*)(smem + 16384);  // 36 KB
    int bxl = blockIdx.x - nScat;
    const bool isP = bxl < cP.blocks;
    const Lin3Cfg& c = isP ? cP : cA;
    const int bx = isP ? bxl : (bxl - cP.blocks);
    const int row0 = bx * 64;
    const int N = c.N;

    #pragma unroll
    for (int ii = 0; ii < 4; ++ii) {
        int ci = threadIdx.x + 256 * ii;
        int r = ci >> 4, k8 = ci & 15;
        int srcrow = row0 + r; if (srcrow >= N) srcrow = N - 1;
        const float4* gp = (const float4*)(c.x + (size_t)srcrow * 128 + k8 * 8);
        float4 v0 = gp[0], v1 = gp[1];
        bf16x8 p;
        p[0] = (short)f2bf(v0.x); p[1] = (short)f2bf(v0.y);
        p[2] = (short)f2bf(v0.z); p[3] = (short)f2bf(v0.w);
        p[4] = (short)f2bf(v1.x); p[5] = (short)f2bf(v1.y);
        p[6] = (short)f2bf(v1.z); p[7] = (short)f2bf(v1.w);
        *(bf16x8*)((char*)xs_s + r * 256 + ((k8 * 16) ^ ((r & 7) << 4))) = p;
    }
    #pragma unroll
    for (int ii = 0; ii < 9; ++ii)
        ((bf16x8*)wl_s)[threadIdx.x + 256 * ii] = c.wfrag[threadIdx.x + 256 * ii];
    __syncthreads();
    mfma_compute_store(xs_s, wl_s, row0, N, c.b0, c.o0, nullptr, c.dA0, c.dB0, c.cd);

    __syncthreads();
    #pragma unroll
    for (int ii = 0; ii < 9; ++ii)
        ((bf16x8*)wl_s)[threadIdx.x + 256 * ii] = c.wfrag[2304 + threadIdx.x + 256 * ii];
    __syncthreads();
    mfma_compute_store(xs_s, wl_s, row0, N, c.b1, nullptr, c.o1, c.dA1, nullptr, c.cd + 8);

    __syncthreads();
    #pragma unroll
    for (int ii = 0; ii < 9; ++ii)
        ((bf16x8*)wl_s)[threadIdx.x + 256 * ii] = c.wfrag[2 * 2304 + threadIdx.x + 256 * ii];
    __syncthreads();
    mfma_compute_store(xs_s, wl_s, row0, N, c.b2, nullptr, c.o2, c.dA2, nullptr, c.cd + 16);
}

// ========== K4: per-bucket CSR finalize ==========
__global__ __launch_bounds__(256) void binB_build_kernel(
    const unsigned* __restrict__ packed, const int* __restrict__ bcnt, const int* __restrict__ bbase,
    int nbkMax, int4 Ns, int E, int stride,
    int* __restrict__ start, int* __restrict__ deg, int* __restrict__ csrc)
{
    int r = blockIdx.y, b = blockIdx.x;
    int N = (r == 0) ? Ns.x : (r == 1) ? Ns.y : (r == 2) ? Ns.z : Ns.w;
    int dst0 = b << 10;
    if (dst0 >= N) return;
    int cnt  = bcnt[r * nbkMax + b];
    int base = bbase[r * nbkMax + b];
    __shared__ int hist[1024];
    __shared__ int sums[256];
    #pragma unroll
    for (int i = 0; i < 4; ++i) hist[threadIdx.x * 4 + i] = 0;
    __syncthreads();
    const unsigned* pk = packed + (size_t)r * E + base;
    for (int i = threadIdx.x; i < cnt; i += 256)
        atomicAdd(&hist[pk[i] & 1023], 1);
    __syncthreads();
    int v4[4], s = 0;
    #pragma unroll
    for (int i = 0; i < 4; ++i) { v4[i] = hist[threadIdx.x * 4 + i]; s += v4[i]; }
    sums[threadIdx.x] = s;
    __syncthreads();
    #pragma unroll
    for (int off = 1; off < 256; off <<= 1) {
        int y = (threadIdx.x >= off) ? sums[threadIdx.x - off] : 0;
        __syncthreads();
        sums[threadIdx.x] += y;
        __syncthreads();
    }
    int run = sums[threadIdx.x] - s;
    int* st = start + (size_t)r * stride;
    int* dg = deg   + (size_t)r * stride;
    #pragma unroll
    for (int i = 0; i < 4; ++i) {
        int idx = threadIdx.x * 4 + i;
        int d = dst0 + idx;
        if (d < N) { dg[d] = v4[i]; st[d] = base + run; }
        hist[idx] = run;
        run += v4[i];
    }
    __syncthreads();
    int* cs = csrc + (size_t)r * E + base;
    for (int i = threadIdx.x; i < cnt; i += 256) {
        unsigned e = pk[i];
        int p = atomicAdd(&hist[e & 1023], 1);
        cs[p] = (int)(e >> 10);
    }
}

// ========== K5: merged per-dst fused GAT (round-8 form: 16 lanes/edge x 4 slots, 2-deep) ==========
struct GatRel {
    const int* start; const int* deg; const int* csrc;
    const unsigned short* Wh; const float* es; const float* ed;
};
struct GatCfg { float* out; int Nd; int blocks; GatRel rel0, rel1; };

__global__ __launch_bounds__(256) void gat_node_kernel(GatCfg cP, GatCfg cA)
{
    const bool isP = blockIdx.x < (unsigned)cP.blocks;
    const GatCfg& c = isP ? cP : cA;
    const int bx = isP ? blockIdx.x : (blockIdx.x - cP.blocks);
    int gid = bx * 256 + threadIdx.x;
    int d = gid >> 6;
    if (d >= c.Nd) return;
    int lane = threadIdx.x & 63;
    int q = lane >> 4;        // edge slot
    int l = lane & 15;        // dim group: dims 8l..8l+7
    int h = l >> 2;           // head

    const float4* orow = (const float4*)(c.out + (size_t)d * 128);
    float4 A0 = orow[l * 2], A1 = orow[l * 2 + 1];

    #pragma unroll
    for (int rel = 0; rel < 2; ++rel) {
        const GatRel& R = rel ? c.rel1 : c.rel0;
        int st = R.start[d];
        int n  = R.deg[d];
        if (n == 0) continue;
        const uint4* W4 = (const uint4*)R.Wh;   // row = 128 bf16 = 16 uint4
        float edv = R.ed[(size_t)d * 4 + h];
        float sum = 0.f;
        float m0 = 0.f, m1 = 0.f, m2 = 0.f, m3 = 0.f;
        float m4 = 0.f, m5 = 0.f, m6 = 0.f, m7 = 0.f;
        int j = q;
        for (; j + 4 < n; j += 8) {
            int s0 = R.csrc[st + j];
            int s1 = R.csrc[st + j + 4];
            float p0 = __expf(leakyf(R.es[(size_t)s0 * 4 + h] + edv));
            float p1 = __expf(leakyf(R.es[(size_t)s1 * 4 + h] + edv));
            uint4 w0 = W4[(size_t)s0 * 16 + l];
            uint4 w1 = W4[(size_t)s1 * 16 + l];
            sum += p0 + p1;
            m0 += p0 * bflo(w0.x) + p1 * bflo(w1.x);
            m1 += p0 * bfhi(w0.x) + p1 * bfhi(w1.x);
            m2 += p0 * bflo(w0.y) + p1 * bflo(w1.y);
            m3 += p0 * bfhi(w0.y) + p1 * bfhi(w1.y);
            m4 += p0 * bflo(w0.z) + p1 * bflo(w1.z);
            m5 += p0 * bfhi(w0.z) + p1 * bfhi(w1.z);
            m6 += p0 * bflo(w0.w) + p1 * bflo(w1.w);
            m7 += p0 * bfhi(w0.w) + p1 * bfhi(w1.w);
        }
        if (j < n) {
            int s0 = R.csrc[st + j];
            float p0 = __expf(leakyf(R.es[(size_t)s0 * 4 + h] + edv));
            uint4 w0 = W4[(size_t)s0 * 16 + l];
            sum += p0;
            m0 += p0 * bflo(w0.x); m1 += p0 * bfhi(w0.x);
            m2 += p0 * bflo(w0.y); m3 += p0 * bfhi(w0.y);
            m4 += p0 * bflo(w0.z); m5 += p0 * bfhi(w0.z);
            m6 += p0 * bflo(w0.w); m7 += p0 * bfhi(w0.w);
        }
        #pragma unroll
        for (int off = 16; off < 64; off <<= 1) {
            sum += __shfl_xor(sum, off, 64);
            m0 += __shfl_xor(m0, off, 64); m1 += __shfl_xor(m1, off, 64);
            m2 += __shfl_xor(m2, off, 64); m3 += __shfl_xor(m3, off, 64);
            m4 += __shfl_xor(m4, off, 64); m5 += __shfl_xor(m5, off, 64);
            m6 += __shfl_xor(m6, off, 64); m7 += __shfl_xor(m7, off, 64);
        }
        float inv = 1.0f / sum;
        A0.x += m0 * inv; A0.y += m1 * inv; A0.z += m2 * inv; A0.w += m3 * inv;
        A1.x += m4 * inv; A1.y += m5 * inv; A1.z += m6 * inv; A1.w += m7 * inv;
    }
    if (lane < 16) {
        A0.x = fmaxf(A0.x, 0.f); A0.y = fmaxf(A0.y, 0.f);
        A0.z = fmaxf(A0.z, 0.f); A0.w = fmaxf(A0.w, 0.f);
        A1.x = fmaxf(A1.x, 0.f); A1.y = fmaxf(A1.y, 0.f);
        A1.z = fmaxf(A1.z, 0.f); A1.w = fmaxf(A1.w, 0.f);
        float4* ow = (float4*)(c.out + (size_t)d * 128);
        ow[l * 2] = A0; ow[l * 2 + 1] = A1;
    }
}

extern "C" void kernel_launch(void* const* d_in, const int* in_sizes, int n_in,
                              void* d_out, int out_size, void* d_ws, size_t ws_size,
                              hipStream_t stream)
{
    const float* feat_P = (const float*)d_in[0];
    const float* feat_A = (const float*)d_in[1];
    const int* src_p2p = (const int*)d_in[2];
    const int* dst_p2p = (const int*)d_in[3];
    const int* src_p2a = (const int*)d_in[4];
    const int* dst_p2a = (const int*)d_in[5];
    const int* src_a2p = (const int*)d_in[6];
    const int* dst_a2p = (const int*)d_in[7];
    const int* src_a2a = (const int*)d_in[8];
    const int* dst_a2a = (const int*)d_in[9];
    const float* W_P   = (const float*)d_in[10]; const float* b_P   = (const float*)d_in[11];
    const float* W_A   = (const float*)d_in[12]; const float* b_A   = (const float*)d_in[13];
    const float* W_p2p = (const float*)d_in[14]; const float* b_p2p = (const float*)d_in[15];
    const float* W_p2a = (const float*)d_in[16]; const float* b_p2a = (const float*)d_in[17];
    const float* W_a2p = (const float*)d_in[18]; const float* b_a2p = (const float*)d_in[19];
    const float* W_a2a = (const float*)d_in[20]; const float* b_a2a = (const float*)d_in[21];
    const float* att_p2p_src = (const float*)d_in[22];
    const float* att_p2p_dst = (const float*)d_in[23];
    const float* att_p2a_src = (const float*)d_in[24];
    const float* att_p2a_dst = (const float*)d_in[25];
    const float* att_a2p_src = (const float*)d_in[26];
    const float* att_a2p_dst = (const float*)d_in[27];
    const float* att_a2a_src = (const float*)d_in[28];
    const float* att_a2a_dst = (const float*)d_in[29];

    const int NP = in_sizes[0] / 128;
    const int NA = in_sizes[1] / 128;
    const int E  = in_sizes[2];
    const int stride = (NP > NA) ? NP : NA;
    const int nbkMax = (stride + 1023) >> 10;   // <= 128
    const int nblkE  = (E + 4095) / 4096;
    const int nCount = 4 * nblkE;

    float* outP = (float*)d_out;
    float* outA = (float*)d_out + (size_t)NP * 128;

    char* ws = (char*)d_ws;
    size_t off = 0;
    auto alloc = [&](size_t bytes) -> void* {
        void* p = ws + off;
        off += (bytes + 255) & ~(size_t)255;
        return p;
    };
    unsigned short* Whp2p = (unsigned short*)alloc((size_t)NP * 128 * 2);
    unsigned short* Whp2a = (unsigned short*)alloc((size_t)NP * 128 * 2);
    unsigned short* Wha2p = (unsigned short*)alloc((size_t)NA * 128 * 2);
    unsigned short* Wha2a = (unsigned short*)alloc((size_t)NA * 128 * 2);
    float* es_p2p = (float*)alloc((size_t)NP * 16);
    float* es_p2a = (float*)alloc((size_t)NP * 16);
    float* es_a2p = (float*)alloc((size_t)NA * 16);
    float* es_a2a = (float*)alloc((size_t)NA * 16);
    float* ed_p2p = (float*)alloc((size_t)NP * 16);
    float* ed_a2p = (float*)alloc((size_t)NP * 16);
    float* ed_p2a = (float*)alloc((size_t)NA * 16);
    float* ed_a2a = (float*)alloc((size_t)NA * 16);
    int* deg    = (int*)alloc((size_t)4 * stride * 4);
    int* start  = (int*)alloc((size_t)4 * stride * 4);
    int* csrc   = (int*)alloc((size_t)4 * E * 4);
    unsigned* packed = (unsigned*)alloc((size_t)4 * E * 4);
    int* bcnt   = (int*)alloc((size_t)4 * nbkMax * 4);
    int* bbase  = (int*)alloc((size_t)4 * nbkMax * 4);
    int* gwptr  = (int*)alloc((size_t)4 * nbkMax * 4);
    int* pcnt   = (int*)alloc((size_t)4 * nblkE * 128 * 4);
    bf16x8* wfrag = (bf16x8*)alloc((size_t)6 * 2304 * 16);
    float* cd     = (float*)alloc((size_t)6 * 8 * 4);

    // relation order: 0=p2p(dst P), 1=a2p(dst P), 2=p2a(dst A), 3=a2a(dst A)
    Ptr4i dsts = {dst_p2p, dst_a2p, dst_p2a, dst_a2a};
    Ptr4i srcs = {src_p2p, src_a2p, src_p2a, src_a2a};
    int4 Ns = make_int4(NP, NP, NA, NA);

    // ---- K1: count partials ∪ weight prep ----
    {
        PrepM m0 = {W_P,   b_P,   att_p2p_dst, att_a2p_dst};
        PrepM m1 = {W_p2p, b_p2p, att_p2p_src, nullptr};
        PrepM m2 = {W_p2a, b_p2a, att_p2a_src, nullptr};
        PrepM m3 = {W_A,   b_A,   att_p2a_dst, att_a2a_dst};
        PrepM m4 = {W_a2p, b_a2p, att_a2p_src, nullptr};
        PrepM m5 = {W_a2a, b_a2a, att_a2a_src, nullptr};
        prep_count_kernel<<<nCount + 24, 256, 0, stream>>>(m0, m1, m2, m3, m4, m5,
            wfrag, cd, dsts, pcnt, nblkE, E, nCount);
    }

    // ---- K2: reduce + scan ----
    scan_kernel<<<1, 512, 0, stream>>>(pcnt, nblkE, bcnt, bbase, gwptr, nbkMax);

    // ---- K3: scatter ∪ merged MFMA linears ----
    {
        Lin3Cfg cP = {feat_P, NP, (NP + 63) / 64, wfrag, cd,
                      b_P, outP, ed_p2p, ed_a2p,
                      b_p2p, Whp2p, es_p2p,
                      b_p2a, Whp2a, es_p2a};
        Lin3Cfg cA = {feat_A, NA, (NA + 63) / 64, wfrag + (size_t)3 * 2304, cd + 24,
                      b_A, outA, ed_p2a, ed_a2a,
                      b_a2p, Wha2p, es_a2p,
                      b_a2a, Wha2a, es_a2a};
        lin3_scatter_kernel<<<nCount + cP.blocks + cA.blocks, 256, 0, stream>>>(
            cP, cA, dsts, srcs, gwptr, packed, nbkMax, E, nCount);
    }

    // ---- K4: per-bucket CSR finalize ----
    binB_build_kernel<<<dim3(nbkMax, 4), 256, 0, stream>>>(packed, bcnt, bbase,
        nbkMax, Ns, E, stride, start, deg, csrc);

    // ---- K5: merged per-dst aggregation (+self +relu) ----
    {
        GatCfg cP = {outP, NP, (NP * 64 + 255) / 256,
            {start + 0 * (size_t)stride, deg + 0 * (size_t)stride, csrc + 0 * (size_t)E, Whp2p, es_p2p, ed_p2p},
            {start + 1 * (size_t)stride, deg + 1 * (size_t)stride, csrc + 1 * (size_t)E, Wha2p, es_a2p, ed_a2p}};
        GatCfg cA = {outA, NA, (NA * 64 + 255) / 256,
            {start + 2 * (size_t)stride, deg + 2 * (size_t)stride, csrc + 2 * (size_t)E, Whp2a, es_p2a, ed_p2a},
            {start + 3 * (size_t)stride, deg + 3 * (size_t)stride, csrc + 3 * (size_t)E, Wha2a, es_a2a, ed_a2a}};
        gat_node_kernel<<<cP.blocks + cA.blocks, 256, 0, stream>>>(cP, cA);
    }
}